// Round 6
// baseline (303.483 us; speedup 1.0000x reference)
//
#include <hip/hip_runtime.h>

// Trilinear table lookup: (x,y)-cell counting sort -> quad-cooperative gather.
//
// unList: [B,3] f32 in [0,1]; table: [128,128,128,8] f32; out: [B,8] f32
//
// R5 evidence: with only an x-plane sort, gathers are L1-misses and the kernel
// is bound by per-CU outstanding-miss capacity x L2 latency (~32 cy/pt).
// Sorting by (x0,y0) cell (16129 bins) makes each bin's gather footprint
// 4 z-rows = 16 KB (L1-resident); a 256-point block spans ~2 bins so lines
// are fetched from L2 once and served from L1 thereafter.

#define DIM 128
#define CH 8
#define BINS2 16129          // 127*127
// ws layout (bytes):
//   [0,      65536)  hist   (u32 x 16129, zeroed each call)
//   [65536, 131072)  cursor (u32 x 16129, fully written by k_scan)
//   [131072, ...  )  rec    (float4 x B : x,y,z,bits(orig))
#define CUR_OFF 65536
#define REC_OFF 131072

__device__ __forceinline__ int key2_of(float ux, float uy) {
    float sx = fminf(fmaxf(ux, 0.0f), 1.0f) * 127.0f;
    float sy = fminf(fmaxf(uy, 0.0f), 1.0f) * 127.0f;
    int x0 = (int)fminf(floorf(sx), 126.0f);
    int y0 = (int)fminf(floorf(sy), 126.0f);
    return x0 * 127 + y0;
}

__global__ __launch_bounds__(256) void k_hist(const float* __restrict__ un,
                                              unsigned* __restrict__ hist, int batch) {
    int stride = gridDim.x * blockDim.x;
    for (int i = blockIdx.x * blockDim.x + threadIdx.x; i < batch; i += stride)
        atomicAdd(&hist[key2_of(un[3 * i], un[3 * i + 1])], 1u);
}

// exclusive scan of 16129 bins -> cursor. One block of 1024 threads, 16 bins each.
__global__ __launch_bounds__(1024) void k_scan(const unsigned* __restrict__ hist,
                                               unsigned* __restrict__ cursor) {
    __shared__ unsigned s[1024];
    int t = threadIdx.x;
    int base = t * 16;
    unsigned loc[16];
    unsigned sum = 0;
#pragma unroll
    for (int j = 0; j < 16; ++j) {
        int k = base + j;
        unsigned h = (k < BINS2) ? hist[k] : 0u;
        loc[j] = sum;
        sum += h;
    }
    s[t] = sum;
    __syncthreads();
    // Hillis-Steele inclusive scan over 1024 partial sums
    for (int off = 1; off < 1024; off <<= 1) {
        unsigned v = (t >= off) ? s[t - off] : 0u;
        __syncthreads();
        s[t] += v;
        __syncthreads();
    }
    unsigned excl = s[t] - sum;
#pragma unroll
    for (int j = 0; j < 16; ++j) {
        int k = base + j;
        if (k < BINS2) cursor[k] = excl + loc[j];
    }
}

__global__ __launch_bounds__(256) void k_scatter(const float* __restrict__ un,
                                                 unsigned* __restrict__ cursor,
                                                 float4* __restrict__ rec, int batch) {
    int stride = gridDim.x * blockDim.x;
    for (int i = blockIdx.x * blockDim.x + threadIdx.x; i < batch; i += stride) {
        float ux = un[3 * i], uy = un[3 * i + 1], uz = un[3 * i + 2];
        int k = key2_of(ux, uy);
        unsigned r = atomicAdd(&cursor[k], 1u);
        rec[r] = make_float4(ux, uy, uz, __uint_as_float((unsigned)i));
    }
}

// Quad-cooperative main: 4 lanes/point, 16 pts/wave-pass, 256 pts/block
// (4 waves x 4 iterations). Sorted order => block's gather set ~4-6 z-rows
// (16-24 KB), L1-resident after first touch.
__global__ __launch_bounds__(256) void k_main(const float4* __restrict__ rec,
                                              const float* __restrict__ table,
                                              float* __restrict__ out, int batch) {
    // XCD-aware swizzle (gridDim.x % 8 == 0 by launch)
    int per = gridDim.x >> 3;
    int pb = blockIdx.x;
    int lb = (pb & 7) * per + (pb >> 3);

    int t = (int)threadIdx.x;
    int lane = t & 63;
    int wave = t >> 6;
    int p = lane >> 2;        // point within wave-pass: 0..15
    int q = lane & 3;         // quad sub-lane

    const float dmax = 127.0f, imax = 126.0f;
    const char* tb = (const char*)table;
    const unsigned qoff = (unsigned)(q << 4);

    int blk = lb * 256 + wave * 16 + p;
#pragma unroll
    for (int j = 0; j < 4; ++j) {
        int i = blk + j * 64;
        if (i >= batch) continue;

        float4 r = rec[i];
        unsigned orig = __float_as_uint(r.w);

        float sx = fminf(fmaxf(r.x, 0.0f), 1.0f) * dmax;
        float sy = fminf(fmaxf(r.y, 0.0f), 1.0f) * dmax;
        float sz = fminf(fmaxf(r.z, 0.0f), 1.0f) * dmax;
        float fx0 = fminf(floorf(sx), imax);
        float fy0 = fminf(floorf(sy), imax);
        float fz0 = fminf(floorf(sz), imax);
        int x0 = (int)fx0, y0 = (int)fy0, z0 = (int)fz0;
        float fx = sx - fx0, fy = sy - fy0, fz = sz - fz0;

        float wzq = (q & 2) ? fz : (1.0f - fz);
        float gx = 1.0f - fx, gy = 1.0f - fy;
        float w0 = gx * gy * wzq;
        float w1 = gx * fy * wzq;
        float w2 = fx * gy * wzq;
        float w3 = fx * fy * wzq;

        unsigned off = (unsigned)(((x0 * DIM + y0) * DIM + z0) * 32) + qoff;

        float4 v0 = *(const float4*)(tb + off);              // (x0  , y0  )
        float4 v1 = *(const float4*)(tb + off + 4096u);      // (x0  , y0+1)
        float4 v2 = *(const float4*)(tb + off + 524288u);    // (x0+1, y0  )
        float4 v3 = *(const float4*)(tb + off + 528384u);    // (x0+1, y0+1)

        float4 acc;
        acc.x = w0 * v0.x + w1 * v1.x + w2 * v2.x + w3 * v3.x;
        acc.y = w0 * v0.y + w1 * v1.y + w2 * v2.y + w3 * v3.y;
        acc.z = w0 * v0.z + w1 * v1.z + w2 * v2.z + w3 * v3.z;
        acc.w = w0 * v0.w + w1 * v1.w + w2 * v2.w + w3 * v3.w;

        acc.x += __shfl_xor(acc.x, 2);
        acc.y += __shfl_xor(acc.y, 2);
        acc.z += __shfl_xor(acc.z, 2);
        acc.w += __shfl_xor(acc.w, 2);

        if (q < 2)
            *reinterpret_cast<float4*>(out + (size_t)orig * CH + (q << 2)) = acc;
    }
}

// Fallback (no workspace): direct gather.
__global__ __launch_bounds__(256) void k_naive(const float* __restrict__ un,
                                               const float* __restrict__ table,
                                               float* __restrict__ out, int batch) {
    int b = blockIdx.x * blockDim.x + threadIdx.x;
    if (b >= batch) return;
    float ux = un[3 * b], uy = un[3 * b + 1], uz = un[3 * b + 2];
    const float dmax = 127.0f, imax = 126.0f;
    float sx = fminf(fmaxf(ux, 0.0f), 1.0f) * dmax;
    float sy = fminf(fmaxf(uy, 0.0f), 1.0f) * dmax;
    float sz = fminf(fmaxf(uz, 0.0f), 1.0f) * dmax;
    float fx0 = fminf(floorf(sx), imax);
    float fy0 = fminf(floorf(sy), imax);
    float fz0 = fminf(floorf(sz), imax);
    int x0 = (int)fx0, y0 = (int)fy0, z0 = (int)fz0;
    float fx = sx - fx0, fy = sy - fy0, fz = sz - fz0;
    float wx[2] = {1.0f - fx, fx};
    float wy[2] = {1.0f - fy, fy};
    float wz0 = 1.0f - fz, wz1 = fz;
    float acc[CH];
#pragma unroll
    for (int c = 0; c < CH; ++c) acc[c] = 0.0f;
#pragma unroll
    for (int bx = 0; bx < 2; ++bx)
#pragma unroll
        for (int by = 0; by < 2; ++by) {
            const float* pp = table + ((size_t)((x0 + bx) * DIM + (y0 + by)) * DIM + z0) * CH;
            float wxy = wx[bx] * wy[by];
            float w0 = wxy * wz0, w1 = wxy * wz1;
            float4 a0 = *reinterpret_cast<const float4*>(pp + 0);
            float4 a1 = *reinterpret_cast<const float4*>(pp + 4);
            float4 b0 = *reinterpret_cast<const float4*>(pp + 8);
            float4 b1 = *reinterpret_cast<const float4*>(pp + 12);
            acc[0] += w0 * a0.x + w1 * b0.x;  acc[1] += w0 * a0.y + w1 * b0.y;
            acc[2] += w0 * a0.z + w1 * b0.z;  acc[3] += w0 * a0.w + w1 * b0.w;
            acc[4] += w0 * a1.x + w1 * b1.x;  acc[5] += w0 * a1.y + w1 * b1.y;
            acc[6] += w0 * a1.z + w1 * b1.z;  acc[7] += w0 * a1.w + w1 * b1.w;
        }
    float4* o = reinterpret_cast<float4*>(out + (size_t)b * CH);
    o[0] = make_float4(acc[0], acc[1], acc[2], acc[3]);
    o[1] = make_float4(acc[4], acc[5], acc[6], acc[7]);
}

extern "C" void kernel_launch(void* const* d_in, const int* in_sizes, int n_in,
                              void* d_out, int out_size, void* d_ws, size_t ws_size,
                              hipStream_t stream) {
    const float* un    = (const float*)d_in[0];
    const float* table = (const float*)d_in[1];
    float* out         = (float*)d_out;
    int batch = in_sizes[0] / 3;

    size_t need = (size_t)REC_OFF + (size_t)batch * 16;
    if (ws_size < need) {
        int grid = (batch + 255) / 256;
        k_naive<<<grid, 256, 0, stream>>>(un, table, out, batch);
        return;
    }

    unsigned* hist   = (unsigned*)d_ws;
    unsigned* cursor = (unsigned*)((char*)d_ws + CUR_OFF);
    float4*   rec    = (float4*)((char*)d_ws + REC_OFF);

    hipMemsetAsync(d_ws, 0, CUR_OFF, stream);            // zero hist only
    k_hist<<<2048, 256, 0, stream>>>(un, hist, batch);
    k_scan<<<1, 1024, 0, stream>>>(hist, cursor);
    k_scatter<<<2048, 256, 0, stream>>>(un, cursor, rec, batch);

    int nmain = (batch + 255) / 256;
    nmain = ((nmain + 7) / 8) * 8;   // multiple of 8 for XCD swizzle
    k_main<<<nmain, 256, 0, stream>>>(rec, table, out, batch);
}

// Round 7
// 129.255 us; speedup vs baseline: 2.3479x; 2.3479x over previous
//
#include <hip/hip_runtime.h>

// Trilinear table lookup: (x, y/4)-bin counting sort -> per-bin LDS-staged gather.
//
// unList: [B,3] f32 in [0,1]; table: [128,128,128,8] f32; out: [B,8] f32
//
// Evidence R3/R5/R6: any gather path that misses L1 is capped by per-CU
// outstanding-miss capacity x L2 latency (~120 us). Fix: one block per
// (x0, y0>>2) bin; stage the bin's whole gather footprint (2 x-planes x
// 5 y-rows x 128 z x 32B = 40 KB, two contiguous 20 KB chunks) into LDS
// with coalesced loads, then gather from LDS (no L1/MSHR involvement).

#define DIM 128
#define CH 8
#define NBIN 4064            // 127 x-cells * 32 y-groups (y0>>2)
#define TBYTES 67108864u     // 128^3 * 8 * 4
#define CHUNK 8192
#define PPT 32
// ws layout (bytes):
//   [0,     16384)  hist   (u32 x 4064, zeroed each call)
//   [16384, 32768)  cursor (u32 x 4064, rewritten by k_scan)
//   [32768, 49152)  base   (u32 x 4065, rewritten by k_scan)
//   [65536, ...  )  rec    (float4 x B : x,y,z,bits(orig))
#define CUR_OFF 16384
#define BASE_OFF 32768
#define REC_OFF 65536

__device__ __forceinline__ int key_of(float ux, float uy) {
    float sx = fminf(fmaxf(ux, 0.0f), 1.0f) * 127.0f;
    float sy = fminf(fmaxf(uy, 0.0f), 1.0f) * 127.0f;
    int x0 = (int)fminf(floorf(sx), 126.0f);
    int y0 = (int)fminf(floorf(sy), 126.0f);
    return x0 * 32 + (y0 >> 2);
}

__global__ __launch_bounds__(256) void k_hist(const float* __restrict__ un,
                                              unsigned* __restrict__ hist, int batch) {
    __shared__ unsigned lh[NBIN];
    for (int i = threadIdx.x; i < NBIN; i += 256) lh[i] = 0;
    __syncthreads();
    int stride = gridDim.x * blockDim.x;
    for (int i = blockIdx.x * blockDim.x + threadIdx.x; i < batch; i += stride)
        atomicAdd(&lh[key_of(un[3 * i], un[3 * i + 1])], 1u);
    __syncthreads();
    for (int i = threadIdx.x; i < NBIN; i += 256)
        if (lh[i]) atomicAdd(&hist[i], lh[i]);
}

// exclusive scan of 4064 bins -> cursor & base (+ base[NBIN] = total)
__global__ __launch_bounds__(1024) void k_scan(const unsigned* __restrict__ hist,
                                               unsigned* __restrict__ cursor,
                                               unsigned* __restrict__ base) {
    __shared__ unsigned s[1024];
    int t = threadIdx.x;
    int b0 = t * 4;
    unsigned loc[4], sum = 0;
#pragma unroll
    for (int j = 0; j < 4; ++j) {
        int k = b0 + j;
        unsigned h = (k < NBIN) ? hist[k] : 0u;
        loc[j] = sum;
        sum += h;
    }
    s[t] = sum;
    __syncthreads();
    for (int off = 1; off < 1024; off <<= 1) {
        unsigned v = (t >= off) ? s[t - off] : 0u;
        __syncthreads();
        s[t] += v;
        __syncthreads();
    }
    unsigned excl = s[t] - sum;
#pragma unroll
    for (int j = 0; j < 4; ++j) {
        int k = b0 + j;
        if (k < NBIN) { base[k] = excl + loc[j]; cursor[k] = excl + loc[j]; }
    }
    if (t == 1023) base[NBIN] = s[1023];
}

__global__ __launch_bounds__(256) void k_scatter(const float* __restrict__ un,
                                                 unsigned* __restrict__ cursor,
                                                 float4* __restrict__ rec, int batch) {
    __shared__ unsigned lh[NBIN];
    __shared__ unsigned lbase[NBIN];
    int t = threadIdx.x;
    for (int i = t; i < NBIN; i += 256) lh[i] = 0;
    __syncthreads();
    int start = blockIdx.x * CHUNK;
    unsigned kr[PPT];
#pragma unroll
    for (int j = 0; j < PPT; ++j) {
        int i = start + j * 256 + t;
        if (i < batch) {
            int k = key_of(un[3 * i], un[3 * i + 1]);
            unsigned r = atomicAdd(&lh[k], 1u);
            kr[j] = (unsigned)k | (r << 12);
        } else kr[j] = 0u;
    }
    __syncthreads();
    for (int i = t; i < NBIN; i += 256)
        lbase[i] = lh[i] ? atomicAdd(&cursor[i], lh[i]) : 0u;
    __syncthreads();
#pragma unroll
    for (int j = 0; j < PPT; ++j) {
        int i = start + j * 256 + t;
        if (i < batch) {
            unsigned k = kr[j] & 4095u, r = kr[j] >> 12;
            float ux = un[3 * i], uy = un[3 * i + 1], uz = un[3 * i + 2];
            rec[lbase[k] + r] = make_float4(ux, uy, uz, __uint_as_float((unsigned)i));
        }
    }
}

// One block per bin. Stage 40 KB (rows (x0, 4g..4g+4) and (x0+1, 4g..4g+4))
// into LDS, then quad-cooperative gather from LDS.
__global__ __launch_bounds__(256) void k_main(const float4* __restrict__ rec,
                                              const float* __restrict__ table,
                                              const unsigned* __restrict__ base,
                                              float* __restrict__ out) {
    __shared__ float4 lds4[2560];   // 40960 B: [0,1280)=x-plane, [1280,2560)=x+1
    char* ldsb = (char*)lds4;
    const char* tb = (const char*)table;

    int g = blockIdx.x;
    int gx = g >> 5, gy2 = g & 31;
    int ybase = gy2 * 4;
    unsigned s = base[g], e = base[g + 1];

    unsigned offA = (unsigned)(gx * 128 + ybase) * 4096u;   // row (gx, ybase)
    unsigned offB = offA + 524288u;                          // +1 x-plane

    for (int i = threadIdx.x; i < 1280; i += 256) {
        unsigned go = offA + (unsigned)i * 16u;
        if (go > TBYTES - 16u) go = TBYTES - 16u;
        lds4[i] = *(const float4*)(tb + go);
    }
    for (int i = threadIdx.x; i < 1280; i += 256) {
        unsigned go = offB + (unsigned)i * 16u;
        if (go > TBYTES - 16u) go = TBYTES - 16u;       // last bin's unread pad row
        lds4[1280 + i] = *(const float4*)(tb + go);
    }
    __syncthreads();

    int t = (int)threadIdx.x;
    int lane = t & 63, wave = t >> 6;
    int p = lane >> 2, q = lane & 3;
    const float dmax = 127.0f, imax = 126.0f;
    const unsigned qoff = (unsigned)(q << 4);

    for (unsigned i0 = s + (unsigned)(wave * 16); i0 < e; i0 += 64u) {
        unsigned i = i0 + (unsigned)p;
        if (i < e) {
            float4 r = rec[i];
            unsigned orig = __float_as_uint(r.w);

            float sx = fminf(fmaxf(r.x, 0.0f), 1.0f) * dmax;
            float sy = fminf(fmaxf(r.y, 0.0f), 1.0f) * dmax;
            float sz = fminf(fmaxf(r.z, 0.0f), 1.0f) * dmax;
            float fx0 = fminf(floorf(sx), imax);
            float fy0 = fminf(floorf(sy), imax);
            float fz0 = fminf(floorf(sz), imax);
            int y0 = (int)fy0, z0 = (int)fz0;
            float fx = sx - fx0, fy = sy - fy0, fz = sz - fz0;

            float wzq = (q & 2) ? fz : (1.0f - fz);
            float gxw = 1.0f - fx, gyw = 1.0f - fy;
            float w0 = gxw * gyw * wzq;   // (x0  , y0  )
            float w1 = gxw * fy  * wzq;   // (x0  , y0+1)
            float w2 = fx  * gyw * wzq;   // (x0+1, y0  )
            float w3 = fx  * fy  * wzq;   // (x0+1, y0+1)

            int dy = y0 - ybase;          // 0..3
            unsigned a = (unsigned)(dy * 4096 + z0 * 32) + qoff;

            float4 v0 = *(const float4*)(ldsb + a);
            float4 v1 = *(const float4*)(ldsb + a + 4096u);
            float4 v2 = *(const float4*)(ldsb + a + 20480u);
            float4 v3 = *(const float4*)(ldsb + a + 24576u);

            float4 acc;
            acc.x = w0 * v0.x + w1 * v1.x + w2 * v2.x + w3 * v3.x;
            acc.y = w0 * v0.y + w1 * v1.y + w2 * v2.y + w3 * v3.y;
            acc.z = w0 * v0.z + w1 * v1.z + w2 * v2.z + w3 * v3.z;
            acc.w = w0 * v0.w + w1 * v1.w + w2 * v2.w + w3 * v3.w;

            acc.x += __shfl_xor(acc.x, 2);
            acc.y += __shfl_xor(acc.y, 2);
            acc.z += __shfl_xor(acc.z, 2);
            acc.w += __shfl_xor(acc.w, 2);

            if (q < 2)
                *reinterpret_cast<float4*>(out + (size_t)orig * CH + (q << 2)) = acc;
        }
    }
}

// Fallback (no workspace): direct gather.
__global__ __launch_bounds__(256) void k_naive(const float* __restrict__ un,
                                               const float* __restrict__ table,
                                               float* __restrict__ out, int batch) {
    int b = blockIdx.x * blockDim.x + threadIdx.x;
    if (b >= batch) return;
    float ux = un[3 * b], uy = un[3 * b + 1], uz = un[3 * b + 2];
    const float dmax = 127.0f, imax = 126.0f;
    float sx = fminf(fmaxf(ux, 0.0f), 1.0f) * dmax;
    float sy = fminf(fmaxf(uy, 0.0f), 1.0f) * dmax;
    float sz = fminf(fmaxf(uz, 0.0f), 1.0f) * dmax;
    float fx0 = fminf(floorf(sx), imax);
    float fy0 = fminf(floorf(sy), imax);
    float fz0 = fminf(floorf(sz), imax);
    int x0 = (int)fx0, y0 = (int)fy0, z0 = (int)fz0;
    float fx = sx - fx0, fy = sy - fy0, fz = sz - fz0;
    float wx[2] = {1.0f - fx, fx};
    float wy[2] = {1.0f - fy, fy};
    float wz0 = 1.0f - fz, wz1 = fz;
    float acc[CH];
#pragma unroll
    for (int c = 0; c < CH; ++c) acc[c] = 0.0f;
#pragma unroll
    for (int bx = 0; bx < 2; ++bx)
#pragma unroll
        for (int by = 0; by < 2; ++by) {
            const float* pp = table + ((size_t)((x0 + bx) * DIM + (y0 + by)) * DIM + z0) * CH;
            float wxy = wx[bx] * wy[by];
            float w0 = wxy * wz0, w1 = wxy * wz1;
            float4 a0 = *reinterpret_cast<const float4*>(pp + 0);
            float4 a1 = *reinterpret_cast<const float4*>(pp + 4);
            float4 b0 = *reinterpret_cast<const float4*>(pp + 8);
            float4 b1 = *reinterpret_cast<const float4*>(pp + 12);
            acc[0] += w0 * a0.x + w1 * b0.x;  acc[1] += w0 * a0.y + w1 * b0.y;
            acc[2] += w0 * a0.z + w1 * b0.z;  acc[3] += w0 * a0.w + w1 * b0.w;
            acc[4] += w0 * a1.x + w1 * b1.x;  acc[5] += w0 * a1.y + w1 * b1.y;
            acc[6] += w0 * a1.z + w1 * b1.z;  acc[7] += w0 * a1.w + w1 * b1.w;
        }
    float4* o = reinterpret_cast<float4*>(out + (size_t)b * CH);
    o[0] = make_float4(acc[0], acc[1], acc[2], acc[3]);
    o[1] = make_float4(acc[4], acc[5], acc[6], acc[7]);
}

extern "C" void kernel_launch(void* const* d_in, const int* in_sizes, int n_in,
                              void* d_out, int out_size, void* d_ws, size_t ws_size,
                              hipStream_t stream) {
    const float* un    = (const float*)d_in[0];
    const float* table = (const float*)d_in[1];
    float* out         = (float*)d_out;
    int batch = in_sizes[0] / 3;

    size_t need = (size_t)REC_OFF + (size_t)batch * 16;
    if (ws_size < need) {
        int grid = (batch + 255) / 256;
        k_naive<<<grid, 256, 0, stream>>>(un, table, out, batch);
        return;
    }

    unsigned* hist   = (unsigned*)d_ws;
    unsigned* cursor = (unsigned*)((char*)d_ws + CUR_OFF);
    unsigned* base   = (unsigned*)((char*)d_ws + BASE_OFF);
    float4*   rec    = (float4*)((char*)d_ws + REC_OFF);

    hipMemsetAsync(d_ws, 0, CUR_OFF, stream);            // zero hist only
    k_hist<<<512, 256, 0, stream>>>(un, hist, batch);
    k_scan<<<1, 1024, 0, stream>>>(hist, cursor, base);
    int nscat = (batch + CHUNK - 1) / CHUNK;
    k_scatter<<<nscat, 256, 0, stream>>>(un, cursor, rec, batch);
    k_main<<<NBIN, 256, 0, stream>>>(rec, table, base, out);
}

// Round 8
// 120.867 us; speedup vs baseline: 2.5109x; 1.0694x over previous
//
#include <hip/hip_runtime.h>

// Trilinear table lookup: (x, y/4)-bin counting sort -> per-bin LDS-staged gather,
// chunk-pipelined so scattered out-stores never stall the loop.
//
// unList: [B,3] f32 in [0,1]; table: [128,128,128,8] f32; out: [B,8] f32
//
// R7 evidence: LDS staging fixed the L2-latency cap (122->97us) but each pass
// still serialized on vmcnt: rec-load(i+1) waited behind pass-i's scattered
// stores (shared FIFO counter, recycled regs). Here each wave preloads 4
// passes of records and prefetches the next 4 BEFORE issuing stores, so
// vmcnt waits cover loads only. LDS gather uses an XOR swizzle (involution,
// a ^= (a>>2)&0x60) to kill the mod-4 z-cell bank conflicts.

#define DIM 128
#define CH 8
#define NBIN 4064            // 127 x-cells * 32 y-groups (y0>>2)
#define TBYTES 67108864u     // 128^3 * 8 * 4
#define CHUNK 8192
#define PPT 32
// ws layout (bytes):
//   [0,     16384)  hist   (u32 x 4064, zeroed each call)
//   [16384, 32768)  cursor (u32 x 4064, rewritten by k_scan)
//   [32768, 49152)  base   (u32 x 4065, rewritten by k_scan)
//   [65536, ...  )  rec    (float4 x B : x,y,z,bits(orig))
#define CUR_OFF 16384
#define BASE_OFF 32768
#define REC_OFF 65536

__device__ __forceinline__ int key_of(float ux, float uy) {
    float sx = fminf(fmaxf(ux, 0.0f), 1.0f) * 127.0f;
    float sy = fminf(fmaxf(uy, 0.0f), 1.0f) * 127.0f;
    int x0 = (int)fminf(floorf(sx), 126.0f);
    int y0 = (int)fminf(floorf(sy), 126.0f);
    return x0 * 32 + (y0 >> 2);
}

__global__ __launch_bounds__(256) void k_hist(const float* __restrict__ un,
                                              unsigned* __restrict__ hist, int batch) {
    __shared__ unsigned lh[NBIN];
    for (int i = threadIdx.x; i < NBIN; i += 256) lh[i] = 0;
    __syncthreads();
    int stride = gridDim.x * blockDim.x;
    for (int i = blockIdx.x * blockDim.x + threadIdx.x; i < batch; i += stride)
        atomicAdd(&lh[key_of(un[3 * i], un[3 * i + 1])], 1u);
    __syncthreads();
    for (int i = threadIdx.x; i < NBIN; i += 256)
        if (lh[i]) atomicAdd(&hist[i], lh[i]);
}

// exclusive scan of 4064 bins -> cursor & base (+ base[NBIN] = total)
__global__ __launch_bounds__(1024) void k_scan(const unsigned* __restrict__ hist,
                                               unsigned* __restrict__ cursor,
                                               unsigned* __restrict__ base) {
    __shared__ unsigned s[1024];
    int t = threadIdx.x;
    int b0 = t * 4;
    unsigned loc[4], sum = 0;
#pragma unroll
    for (int j = 0; j < 4; ++j) {
        int k = b0 + j;
        unsigned h = (k < NBIN) ? hist[k] : 0u;
        loc[j] = sum;
        sum += h;
    }
    s[t] = sum;
    __syncthreads();
    for (int off = 1; off < 1024; off <<= 1) {
        unsigned v = (t >= off) ? s[t - off] : 0u;
        __syncthreads();
        s[t] += v;
        __syncthreads();
    }
    unsigned excl = s[t] - sum;
#pragma unroll
    for (int j = 0; j < 4; ++j) {
        int k = b0 + j;
        if (k < NBIN) { base[k] = excl + loc[j]; cursor[k] = excl + loc[j]; }
    }
    if (t == 1023) base[NBIN] = s[1023];
}

__global__ __launch_bounds__(256) void k_scatter(const float* __restrict__ un,
                                                 unsigned* __restrict__ cursor,
                                                 float4* __restrict__ rec, int batch) {
    __shared__ unsigned lh[NBIN];
    __shared__ unsigned lbase[NBIN];
    int t = threadIdx.x;
    for (int i = t; i < NBIN; i += 256) lh[i] = 0;
    __syncthreads();
    int start = blockIdx.x * CHUNK;
    unsigned kr[PPT];
#pragma unroll
    for (int j = 0; j < PPT; ++j) {
        int i = start + j * 256 + t;
        if (i < batch) {
            int k = key_of(un[3 * i], un[3 * i + 1]);
            unsigned r = atomicAdd(&lh[k], 1u);
            kr[j] = (unsigned)k | (r << 12);
        } else kr[j] = 0u;
    }
    __syncthreads();
    for (int i = t; i < NBIN; i += 256)
        lbase[i] = lh[i] ? atomicAdd(&cursor[i], lh[i]) : 0u;
    __syncthreads();
#pragma unroll
    for (int j = 0; j < PPT; ++j) {
        int i = start + j * 256 + t;
        if (i < batch) {
            unsigned k = kr[j] & 4095u, r = kr[j] >> 12;
            float ux = un[3 * i], uy = un[3 * i + 1], uz = un[3 * i + 2];
            rec[lbase[k] + r] = make_float4(ux, uy, uz, __uint_as_float((unsigned)i));
        }
    }
}

// One block per bin. Stage 40 KB (x-planes x0/x0+1, rows ybase..ybase+4, swizzled)
// into LDS, then quad-cooperative gather from LDS with 4-pass chunk pipelining.
__global__ __launch_bounds__(256) void k_main(const float4* __restrict__ rec,
                                              const float* __restrict__ table,
                                              const unsigned* __restrict__ base,
                                              float* __restrict__ out) {
    __shared__ float4 lds4[2560];   // 40960 B: [0,20480)=x-plane, [20480,40960)=x+1
    char* ldsb = (char*)lds4;
    const char* tb = (const char*)table;

    int g = blockIdx.x;
    int gx = g >> 5, gy2 = g & 31;
    int ybase = gy2 * 4;
    unsigned s = base[g], e = base[g + 1];

    unsigned offA = (unsigned)(gx * 128 + ybase) * 4096u;   // row (gx, ybase)
    unsigned offB = offA + 524288u;                          // +1 x-plane

    for (int i = threadIdx.x; i < 1280; i += 256) {
        unsigned wa = (unsigned)i * 16u;
        unsigned sa = wa ^ ((wa >> 2) & 0x60u);   // bank swizzle (involution)
        unsigned go = offA + wa;
        if (go > TBYTES - 16u) go = TBYTES - 16u;
        *(float4*)(ldsb + sa) = *(const float4*)(tb + go);
        go = offB + wa;
        if (go > TBYTES - 16u) go = TBYTES - 16u;  // last bin's unused pad row
        *(float4*)(ldsb + 20480u + sa) = *(const float4*)(tb + go);
    }
    __syncthreads();
    if (e <= s) return;   // empty bin (no further barriers)

    int t = (int)threadIdx.x;
    int lane = t & 63, wave = t >> 6;
    int p = lane >> 2, q = lane & 3;
    const float dmax = 127.0f, imax = 126.0f;
    const unsigned qoff = (unsigned)(q << 4);
    const unsigned last = e - 1u;

    unsigned myi = s + (unsigned)(wave * 16 + p);
    unsigned cnt = e - s;

#define PROC(rr, idx) { \
        if ((idx) < e) { \
            unsigned orig = __float_as_uint(rr.w); \
            float sx = fminf(fmaxf(rr.x, 0.0f), 1.0f) * dmax; \
            float sy = fminf(fmaxf(rr.y, 0.0f), 1.0f) * dmax; \
            float sz = fminf(fmaxf(rr.z, 0.0f), 1.0f) * dmax; \
            float fx0 = fminf(floorf(sx), imax); \
            float fy0 = fminf(floorf(sy), imax); \
            float fz0 = fminf(floorf(sz), imax); \
            int y0 = (int)fy0, z0 = (int)fz0; \
            float fx = sx - fx0, fy = sy - fy0, fz = sz - fz0; \
            float wzq = (q & 2) ? fz : (1.0f - fz); \
            float gxw = 1.0f - fx, gyw = 1.0f - fy; \
            float w0 = gxw * gyw * wzq; \
            float w1 = gxw * fy  * wzq; \
            float w2 = fx  * gyw * wzq; \
            float w3 = fx  * fy  * wzq; \
            int dy = y0 - ybase; \
            unsigned a = (unsigned)(dy * 4096 + z0 * 32) + qoff; \
            unsigned sa = a ^ ((a >> 2) & 0x60u); \
            float4 v0 = *(const float4*)(ldsb + sa); \
            float4 v1 = *(const float4*)(ldsb + sa + 4096u); \
            float4 v2 = *(const float4*)(ldsb + sa + 20480u); \
            float4 v3 = *(const float4*)(ldsb + sa + 24576u); \
            float4 acc; \
            acc.x = w0 * v0.x + w1 * v1.x + w2 * v2.x + w3 * v3.x; \
            acc.y = w0 * v0.y + w1 * v1.y + w2 * v2.y + w3 * v3.y; \
            acc.z = w0 * v0.z + w1 * v1.z + w2 * v2.z + w3 * v3.z; \
            acc.w = w0 * v0.w + w1 * v1.w + w2 * v2.w + w3 * v3.w; \
            acc.x += __shfl_xor(acc.x, 2); \
            acc.y += __shfl_xor(acc.y, 2); \
            acc.z += __shfl_xor(acc.z, 2); \
            acc.w += __shfl_xor(acc.w, 2); \
            if (q < 2) \
                *reinterpret_cast<float4*>(out + (size_t)orig * CH + (q << 2)) = acc; \
        } }

    // preload chunk 0 (4 passes), clamped
    float4 r0 = rec[min(myi +   0u, last)];
    float4 r1 = rec[min(myi +  64u, last)];
    float4 r2 = rec[min(myi + 128u, last)];
    float4 r3 = rec[min(myi + 192u, last)];

    for (unsigned c0 = 0; c0 < cnt; c0 += 256u) {
        // prefetch next chunk BEFORE any stores of this chunk
        float4 n0 = rec[min(myi + c0 + 256u, last)];
        float4 n1 = rec[min(myi + c0 + 320u, last)];
        float4 n2 = rec[min(myi + c0 + 384u, last)];
        float4 n3 = rec[min(myi + c0 + 448u, last)];
        PROC(r0, myi + c0 +   0u)
        PROC(r1, myi + c0 +  64u)
        PROC(r2, myi + c0 + 128u)
        PROC(r3, myi + c0 + 192u)
        r0 = n0; r1 = n1; r2 = n2; r3 = n3;
    }
#undef PROC
}

// Fallback (no workspace): direct gather.
__global__ __launch_bounds__(256) void k_naive(const float* __restrict__ un,
                                               const float* __restrict__ table,
                                               float* __restrict__ out, int batch) {
    int b = blockIdx.x * blockDim.x + threadIdx.x;
    if (b >= batch) return;
    float ux = un[3 * b], uy = un[3 * b + 1], uz = un[3 * b + 2];
    const float dmax = 127.0f, imax = 126.0f;
    float sx = fminf(fmaxf(ux, 0.0f), 1.0f) * dmax;
    float sy = fminf(fmaxf(uy, 0.0f), 1.0f) * dmax;
    float sz = fminf(fmaxf(uz, 0.0f), 1.0f) * dmax;
    float fx0 = fminf(floorf(sx), imax);
    float fy0 = fminf(floorf(sy), imax);
    float fz0 = fminf(floorf(sz), imax);
    int x0 = (int)fx0, y0 = (int)fy0, z0 = (int)fz0;
    float fx = sx - fx0, fy = sy - fy0, fz = sz - fz0;
    float wx[2] = {1.0f - fx, fx};
    float wy[2] = {1.0f - fy, fy};
    float wz0 = 1.0f - fz, wz1 = fz;
    float acc[CH];
#pragma unroll
    for (int c = 0; c < CH; ++c) acc[c] = 0.0f;
#pragma unroll
    for (int bx = 0; bx < 2; ++bx)
#pragma unroll
        for (int by = 0; by < 2; ++by) {
            const float* pp = table + ((size_t)((x0 + bx) * DIM + (y0 + by)) * DIM + z0) * CH;
            float wxy = wx[bx] * wy[by];
            float w0 = wxy * wz0, w1 = wxy * wz1;
            float4 a0 = *reinterpret_cast<const float4*>(pp + 0);
            float4 a1 = *reinterpret_cast<const float4*>(pp + 4);
            float4 b0 = *reinterpret_cast<const float4*>(pp + 8);
            float4 b1 = *reinterpret_cast<const float4*>(pp + 12);
            acc[0] += w0 * a0.x + w1 * b0.x;  acc[1] += w0 * a0.y + w1 * b0.y;
            acc[2] += w0 * a0.z + w1 * b0.z;  acc[3] += w0 * a0.w + w1 * b0.w;
            acc[4] += w0 * a1.x + w1 * b1.x;  acc[5] += w0 * a1.y + w1 * b1.y;
            acc[6] += w0 * a1.z + w1 * b1.z;  acc[7] += w0 * a1.w + w1 * b1.w;
        }
    float4* o = reinterpret_cast<float4*>(out + (size_t)b * CH);
    o[0] = make_float4(acc[0], acc[1], acc[2], acc[3]);
    o[1] = make_float4(acc[4], acc[5], acc[6], acc[7]);
}

extern "C" void kernel_launch(void* const* d_in, const int* in_sizes, int n_in,
                              void* d_out, int out_size, void* d_ws, size_t ws_size,
                              hipStream_t stream) {
    const float* un    = (const float*)d_in[0];
    const float* table = (const float*)d_in[1];
    float* out         = (float*)d_out;
    int batch = in_sizes[0] / 3;

    size_t need = (size_t)REC_OFF + (size_t)batch * 16;
    if (ws_size < need) {
        int grid = (batch + 255) / 256;
        k_naive<<<grid, 256, 0, stream>>>(un, table, out, batch);
        return;
    }

    unsigned* hist   = (unsigned*)d_ws;
    unsigned* cursor = (unsigned*)((char*)d_ws + CUR_OFF);
    unsigned* base   = (unsigned*)((char*)d_ws + BASE_OFF);
    float4*   rec    = (float4*)((char*)d_ws + REC_OFF);

    hipMemsetAsync(d_ws, 0, CUR_OFF, stream);            // zero hist only
    k_hist<<<512, 256, 0, stream>>>(un, hist, batch);
    k_scan<<<1, 1024, 0, stream>>>(hist, cursor, base);
    int nscat = (batch + CHUNK - 1) / CHUNK;
    k_scatter<<<nscat, 256, 0, stream>>>(un, cursor, rec, batch);
    k_main<<<NBIN, 256, 0, stream>>>(rec, table, base, out);
}

// Round 9
// 119.959 us; speedup vs baseline: 2.5299x; 1.0076x over previous
//
#include <hip/hip_runtime.h>

// Trilinear table lookup: (x, y/4)-bin counting sort -> per-bin LDS-staged gather.
//
// unList: [B,3] f32 in [0,1]; table: [128,128,128,8] f32; out: [B,8] f32
//
// R8 evidence: VGPR=52 proved the compiler defeated both the staging pipeline
// and the rec prefetch (register budget targeted 8 waves/EU while LDS caps us
// at 4). Fixes: __launch_bounds__(256,4) to unlock 128 VGPRs, and staging via
// global_load_lds (zero-VGPR direct-to-LDS DMA, all chunks in flight).

#define DIM 128
#define CH 8
#define NBIN 4064            // 127 x-cells * 32 y-groups (y0>>2)
#define TBYTES 67108864u     // 128^3 * 8 * 4
#define CHUNK 8192
#define PPT 32
// ws layout (bytes):
//   [0,     16384)  hist   (u32 x 4064, zeroed each call)
//   [16384, 32768)  cursor (u32 x 4064, rewritten by k_scan)
//   [32768, 49152)  base   (u32 x 4065, rewritten by k_scan)
//   [65536, ...  )  rec    (float4 x B : x,y,z,bits(orig))
#define CUR_OFF 16384
#define BASE_OFF 32768
#define REC_OFF 65536

__device__ __forceinline__ int key_of(float ux, float uy) {
    float sx = fminf(fmaxf(ux, 0.0f), 1.0f) * 127.0f;
    float sy = fminf(fmaxf(uy, 0.0f), 1.0f) * 127.0f;
    int x0 = (int)fminf(floorf(sx), 126.0f);
    int y0 = (int)fminf(floorf(sy), 126.0f);
    return x0 * 32 + (y0 >> 2);
}

__global__ __launch_bounds__(256) void k_hist(const float* __restrict__ un,
                                              unsigned* __restrict__ hist, int batch) {
    __shared__ unsigned lh[NBIN];
    for (int i = threadIdx.x; i < NBIN; i += 256) lh[i] = 0;
    __syncthreads();
    int stride = gridDim.x * blockDim.x;
    for (int i = blockIdx.x * blockDim.x + threadIdx.x; i < batch; i += stride)
        atomicAdd(&lh[key_of(un[3 * i], un[3 * i + 1])], 1u);
    __syncthreads();
    for (int i = threadIdx.x; i < NBIN; i += 256)
        if (lh[i]) atomicAdd(&hist[i], lh[i]);
}

// exclusive scan of 4064 bins -> cursor & base (+ base[NBIN] = total)
__global__ __launch_bounds__(1024) void k_scan(const unsigned* __restrict__ hist,
                                               unsigned* __restrict__ cursor,
                                               unsigned* __restrict__ base) {
    __shared__ unsigned s[1024];
    int t = threadIdx.x;
    int b0 = t * 4;
    unsigned loc[4], sum = 0;
#pragma unroll
    for (int j = 0; j < 4; ++j) {
        int k = b0 + j;
        unsigned h = (k < NBIN) ? hist[k] : 0u;
        loc[j] = sum;
        sum += h;
    }
    s[t] = sum;
    __syncthreads();
    for (int off = 1; off < 1024; off <<= 1) {
        unsigned v = (t >= off) ? s[t - off] : 0u;
        __syncthreads();
        s[t] += v;
        __syncthreads();
    }
    unsigned excl = s[t] - sum;
#pragma unroll
    for (int j = 0; j < 4; ++j) {
        int k = b0 + j;
        if (k < NBIN) { base[k] = excl + loc[j]; cursor[k] = excl + loc[j]; }
    }
    if (t == 1023) base[NBIN] = s[1023];
}

__global__ __launch_bounds__(256) void k_scatter(const float* __restrict__ un,
                                                 unsigned* __restrict__ cursor,
                                                 float4* __restrict__ rec, int batch) {
    __shared__ unsigned lh[NBIN];
    __shared__ unsigned lbase[NBIN];
    int t = threadIdx.x;
    for (int i = t; i < NBIN; i += 256) lh[i] = 0;
    __syncthreads();
    int start = blockIdx.x * CHUNK;
    unsigned kr[PPT];
#pragma unroll
    for (int j = 0; j < PPT; ++j) {
        int i = start + j * 256 + t;
        if (i < batch) {
            int k = key_of(un[3 * i], un[3 * i + 1]);
            unsigned r = atomicAdd(&lh[k], 1u);
            kr[j] = (unsigned)k | (r << 12);
        } else kr[j] = 0u;
    }
    __syncthreads();
    for (int i = t; i < NBIN; i += 256)
        lbase[i] = lh[i] ? atomicAdd(&cursor[i], lh[i]) : 0u;
    __syncthreads();
#pragma unroll
    for (int j = 0; j < PPT; ++j) {
        int i = start + j * 256 + t;
        if (i < batch) {
            unsigned k = kr[j] & 4095u, r = kr[j] >> 12;
            float ux = un[3 * i], uy = un[3 * i + 1], uz = un[3 * i + 2];
            rec[lbase[k] + r] = make_float4(ux, uy, uz, __uint_as_float((unsigned)i));
        }
    }
}

// One block per bin. Stage 40 KB (x-planes x0/x0+1, rows ybase..ybase+4) into
// LDS via global_load_lds DMA, then quad-cooperative gather with 4-deep
// rec prefetch. 4 waves/EU declared -> up to 128 VGPRs.
__global__ __launch_bounds__(256, 4) void k_main(const float4* __restrict__ rec,
                                                 const float* __restrict__ table,
                                                 const unsigned* __restrict__ base,
                                                 float* __restrict__ out) {
    __shared__ float4 lds4[2560];   // 40960 B: [0,20480)=x-plane, [20480,40960)=x+1
    char* ldsb = (char*)lds4;
    const char* tb = (const char*)table;

    int g = blockIdx.x;
    int gx = g >> 5, gy2 = g & 31;
    int ybase = gy2 * 4;
    unsigned s = base[g], e = base[g + 1];

    unsigned offA = (unsigned)(gx * 128 + ybase) * 4096u;   // row (gx, ybase)
    unsigned offB = offA + 524288u;                          // +1 x-plane

    int t = (int)threadIdx.x;
    int lane = t & 63, wave = t >> 6;

    // 40 chunks of 1024 B; wave w stages chunks {w, w+4, ..., w+36}.
    // LDS dest is wave-uniform base; HW writes lane ln -> base + ln*16.
#pragma unroll
    for (int j = 0; j < 10; ++j) {
        int c = wave + j * 4;
        unsigned lo = (unsigned)c * 1024u;
        unsigned go = (c < 20) ? (offA + lo) : (offB + (lo - 20480u));
        go += (unsigned)lane * 16u;
        if (go > TBYTES - 16u) go = TBYTES - 16u;   // last bins' pad rows
        __builtin_amdgcn_global_load_lds(
            (const __attribute__((address_space(1))) void*)(tb + go),
            (__attribute__((address_space(3))) void*)(ldsb + lo), 16, 0, 0);
    }
    __syncthreads();
    if (e <= s) return;   // empty bin (after barrier)

    int p = lane >> 2, q = lane & 3;
    const float dmax = 127.0f, imax = 126.0f;
    const unsigned qoff = (unsigned)(q << 4);
    const unsigned last = e - 1u;

    unsigned myi = s + (unsigned)(wave * 16 + p);
    unsigned cnt = e - s;

#define PROC(rr, idx) { \
        if ((idx) < e) { \
            unsigned orig = __float_as_uint(rr.w); \
            float sx = fminf(fmaxf(rr.x, 0.0f), 1.0f) * dmax; \
            float sy = fminf(fmaxf(rr.y, 0.0f), 1.0f) * dmax; \
            float sz = fminf(fmaxf(rr.z, 0.0f), 1.0f) * dmax; \
            float fx0 = fminf(floorf(sx), imax); \
            float fy0 = fminf(floorf(sy), imax); \
            float fz0 = fminf(floorf(sz), imax); \
            int y0 = (int)fy0, z0 = (int)fz0; \
            float fx = sx - fx0, fy = sy - fy0, fz = sz - fz0; \
            float wzq = (q & 2) ? fz : (1.0f - fz); \
            float gxw = 1.0f - fx, gyw = 1.0f - fy; \
            float w0 = gxw * gyw * wzq; \
            float w1 = gxw * fy  * wzq; \
            float w2 = fx  * gyw * wzq; \
            float w3 = fx  * fy  * wzq; \
            int dy = y0 - ybase; \
            unsigned a = (unsigned)(dy * 4096 + z0 * 32) + qoff; \
            float4 v0 = *(const float4*)(ldsb + a); \
            float4 v1 = *(const float4*)(ldsb + a + 4096u); \
            float4 v2 = *(const float4*)(ldsb + a + 20480u); \
            float4 v3 = *(const float4*)(ldsb + a + 24576u); \
            float4 acc; \
            acc.x = w0 * v0.x + w1 * v1.x + w2 * v2.x + w3 * v3.x; \
            acc.y = w0 * v0.y + w1 * v1.y + w2 * v2.y + w3 * v3.y; \
            acc.z = w0 * v0.z + w1 * v1.z + w2 * v2.z + w3 * v3.z; \
            acc.w = w0 * v0.w + w1 * v1.w + w2 * v2.w + w3 * v3.w; \
            acc.x += __shfl_xor(acc.x, 2); \
            acc.y += __shfl_xor(acc.y, 2); \
            acc.z += __shfl_xor(acc.z, 2); \
            acc.w += __shfl_xor(acc.w, 2); \
            if (q < 2) \
                *reinterpret_cast<float4*>(out + (size_t)orig * CH + (q << 2)) = acc; \
        } }

    // preload chunk 0 (4 passes), clamped
    float4 r0 = rec[min(myi +   0u, last)];
    float4 r1 = rec[min(myi +  64u, last)];
    float4 r2 = rec[min(myi + 128u, last)];
    float4 r3 = rec[min(myi + 192u, last)];

    for (unsigned c0 = 0; c0 < cnt; c0 += 256u) {
        // prefetch next chunk BEFORE any stores of this chunk
        float4 n0 = rec[min(myi + c0 + 256u, last)];
        float4 n1 = rec[min(myi + c0 + 320u, last)];
        float4 n2 = rec[min(myi + c0 + 384u, last)];
        float4 n3 = rec[min(myi + c0 + 448u, last)];
        PROC(r0, myi + c0 +   0u)
        PROC(r1, myi + c0 +  64u)
        PROC(r2, myi + c0 + 128u)
        PROC(r3, myi + c0 + 192u)
        r0 = n0; r1 = n1; r2 = n2; r3 = n3;
    }
#undef PROC
}

// Fallback (no workspace): direct gather.
__global__ __launch_bounds__(256) void k_naive(const float* __restrict__ un,
                                               const float* __restrict__ table,
                                               float* __restrict__ out, int batch) {
    int b = blockIdx.x * blockDim.x + threadIdx.x;
    if (b >= batch) return;
    float ux = un[3 * b], uy = un[3 * b + 1], uz = un[3 * b + 2];
    const float dmax = 127.0f, imax = 126.0f;
    float sx = fminf(fmaxf(ux, 0.0f), 1.0f) * dmax;
    float sy = fminf(fmaxf(uy, 0.0f), 1.0f) * dmax;
    float sz = fminf(fmaxf(uz, 0.0f), 1.0f) * dmax;
    float fx0 = fminf(floorf(sx), imax);
    float fy0 = fminf(floorf(sy), imax);
    float fz0 = fminf(floorf(sz), imax);
    int x0 = (int)fx0, y0 = (int)fy0, z0 = (int)fz0;
    float fx = sx - fx0, fy = sy - fy0, fz = sz - fz0;
    float wx[2] = {1.0f - fx, fx};
    float wy[2] = {1.0f - fy, fy};
    float wz0 = 1.0f - fz, wz1 = fz;
    float acc[CH];
#pragma unroll
    for (int c = 0; c < CH; ++c) acc[c] = 0.0f;
#pragma unroll
    for (int bx = 0; bx < 2; ++bx)
#pragma unroll
        for (int by = 0; by < 2; ++by) {
            const float* pp = table + ((size_t)((x0 + bx) * DIM + (y0 + by)) * DIM + z0) * CH;
            float wxy = wx[bx] * wy[by];
            float w0 = wxy * wz0, w1 = wxy * wz1;
            float4 a0 = *reinterpret_cast<const float4*>(pp + 0);
            float4 a1 = *reinterpret_cast<const float4*>(pp + 4);
            float4 b0 = *reinterpret_cast<const float4*>(pp + 8);
            float4 b1 = *reinterpret_cast<const float4*>(pp + 12);
            acc[0] += w0 * a0.x + w1 * b0.x;  acc[1] += w0 * a0.y + w1 * b0.y;
            acc[2] += w0 * a0.z + w1 * b0.z;  acc[3] += w0 * a0.w + w1 * b0.w;
            acc[4] += w0 * a1.x + w1 * b1.x;  acc[5] += w0 * a1.y + w1 * b1.y;
            acc[6] += w0 * a1.z + w1 * b1.z;  acc[7] += w0 * a1.w + w1 * b1.w;
        }
    float4* o = reinterpret_cast<float4*>(out + (size_t)b * CH);
    o[0] = make_float4(acc[0], acc[1], acc[2], acc[3]);
    o[1] = make_float4(acc[4], acc[5], acc[6], acc[7]);
}

extern "C" void kernel_launch(void* const* d_in, const int* in_sizes, int n_in,
                              void* d_out, int out_size, void* d_ws, size_t ws_size,
                              hipStream_t stream) {
    const float* un    = (const float*)d_in[0];
    const float* table = (const float*)d_in[1];
    float* out         = (float*)d_out;
    int batch = in_sizes[0] / 3;

    size_t need = (size_t)REC_OFF + (size_t)batch * 16;
    if (ws_size < need) {
        int grid = (batch + 255) / 256;
        k_naive<<<grid, 256, 0, stream>>>(un, table, out, batch);
        return;
    }

    unsigned* hist   = (unsigned*)d_ws;
    unsigned* cursor = (unsigned*)((char*)d_ws + CUR_OFF);
    unsigned* base   = (unsigned*)((char*)d_ws + BASE_OFF);
    float4*   rec    = (float4*)((char*)d_ws + REC_OFF);

    hipMemsetAsync(d_ws, 0, CUR_OFF, stream);            // zero hist only
    k_hist<<<512, 256, 0, stream>>>(un, hist, batch);
    k_scan<<<1, 1024, 0, stream>>>(hist, cursor, base);
    int nscat = (batch + CHUNK - 1) / CHUNK;
    k_scatter<<<nscat, 256, 0, stream>>>(un, cursor, rec, batch);
    k_main<<<NBIN, 256, 0, stream>>>(rec, table, base, out);
}